// Round 1
// baseline (222.524 us; speedup 1.0000x reference)
//
#include <hip/hip_runtime.h>

#define SEQ  2048
#define EMB  512
#define NH   8
#define FEAT 64
// window: j = 0..64, key pos = s - 128 + 4*j

// ---------------------------------------------------------------------------
// GEMM: C[M,N] = A[M,K] * B[K,N]  (+bias, relu, +addsrc)
// BM=64, BN=64, BK=32, block=512 threads, per-thread 4x2 outputs.
// ---------------------------------------------------------------------------
template<bool HASBIAS, bool RELU, bool ADDSRC>
__global__ __launch_bounds__(512)
void gemm64(const float* __restrict__ A, const float* __restrict__ B,
            const float* __restrict__ bias, const float* __restrict__ addsrc,
            float* __restrict__ C, int M, int N, int K)
{
    __shared__ float As[32][68];   // [k][m], padded: store-conflicts <= 4-way
    __shared__ float Bs[32][64];   // [k][n]
    const int tid = threadIdx.x;
    const int n0 = blockIdx.x * 64;
    const int m0 = blockIdx.y * 64;
    const int tn = tid & 31;       // cols 2*tn..+1
    const int tm = tid >> 5;       // rows 4*tm..+3
    const int am = tid >> 3;       // 0..63
    const int ak = (tid & 7) * 4;  // 0..28
    const int bk = tid >> 4;       // 0..31
    const int bn = (tid & 15) * 4; // 0..60

    float acc[4][2] = {};

    for (int kt = 0; kt < K; kt += 32) {
        float4 av = *(const float4*)&A[(m0 + am) * K + kt + ak];
        float4 bv = *(const float4*)&B[(kt + bk) * N + n0 + bn];
        __syncthreads();   // previous compute done before LDS overwrite
        As[ak + 0][am] = av.x;
        As[ak + 1][am] = av.y;
        As[ak + 2][am] = av.z;
        As[ak + 3][am] = av.w;
        *(float4*)&Bs[bk][bn] = bv;
        __syncthreads();
        #pragma unroll
        for (int k = 0; k < 32; ++k) {
            float4 a = *(const float4*)&As[k][tm * 4];
            float2 b = *(const float2*)&Bs[k][tn * 2];
            acc[0][0] += a.x * b.x;  acc[0][1] += a.x * b.y;
            acc[1][0] += a.y * b.x;  acc[1][1] += a.y * b.y;
            acc[2][0] += a.z * b.x;  acc[2][1] += a.z * b.y;
            acc[3][0] += a.w * b.x;  acc[3][1] += a.w * b.y;
        }
    }

    float2 bia = make_float2(0.f, 0.f);
    if (HASBIAS) bia = *(const float2*)&bias[n0 + tn * 2];
    #pragma unroll
    for (int r = 0; r < 4; ++r) {
        int row = m0 + tm * 4 + r;
        float2 o = make_float2(acc[r][0], acc[r][1]);
        if (HASBIAS) { o.x += bia.x; o.y += bia.y; }
        if (RELU)    { o.x = fmaxf(o.x, 0.f); o.y = fmaxf(o.y, 0.f); }
        if (ADDSRC)  { float2 s = *(const float2*)&addsrc[row * N + n0 + tn * 2];
                       o.x += s.x; o.y += s.y; }
        *(float2*)&C[row * N + n0 + tn * 2] = o;
    }
}

// ---------------------------------------------------------------------------
// Dilated sliding-window attention.
// Block handles (head h, residue r, 32 queries s = s0 + 4*i).
// Keys/values needed: rows t = i + j in [0,95], pos p = s0 - 128 + 4*t.
// OOB rows zero-filled -> logit == 0 exactly, matching the reference pad.
// softmax over 65 logits, then *1/8 (reference divides AFTER softmax).
// ---------------------------------------------------------------------------
__global__ __launch_bounds__(256)
void attn_kernel(const float* __restrict__ Q, const float* __restrict__ K,
                 const float* __restrict__ V, float* __restrict__ X)
{
    const int c = blockIdx.x;           // 0..15 chunk
    const int r = blockIdx.y;           // 0..3 residue
    const int h = blockIdx.z;           // 0..7 head
    const int tid = threadIdx.x;
    const int s0 = r + 4 * (c * 32);    // query i -> s = s0 + 4*i

    __shared__ float qs[32][68];        // pad: q broadcast reads conflict-free
    __shared__ float ks[96][65];        // pad 65: row-striding reads 2-way max
    __shared__ float vs[96][65];
    __shared__ float lg[32][66];

    // load Q tile
    for (int t = tid; t < 32 * 16; t += 256) {
        int i = t >> 4, fq = (t & 15) * 4;
        float4 v4 = *(const float4*)&Q[(s0 + 4 * i) * EMB + h * FEAT + fq];
        *(float4*)&qs[i][fq] = v4;
    }
    // load K/V tiles (zero-fill out-of-range rows)
    for (int t = tid; t < 96 * 16; t += 256) {
        int row = t >> 4, fq = (t & 15) * 4;
        int p = s0 - 128 + 4 * row;
        float4 kv = make_float4(0.f, 0.f, 0.f, 0.f);
        float4 vv = make_float4(0.f, 0.f, 0.f, 0.f);
        if (p >= 0 && p < SEQ) {
            kv = *(const float4*)&K[p * EMB + h * FEAT + fq];
            vv = *(const float4*)&V[p * EMB + h * FEAT + fq];
        }
        ks[row][fq + 0] = kv.x; ks[row][fq + 1] = kv.y;
        ks[row][fq + 2] = kv.z; ks[row][fq + 3] = kv.w;
        vs[row][fq + 0] = vv.x; vs[row][fq + 1] = vv.y;
        vs[row][fq + 2] = vv.z; vs[row][fq + 3] = vv.w;
    }
    __syncthreads();

    // QK logits: thread (i = tid>>3, jq = tid&7) computes j = 8*jq + v, v=0..7
    {
        const int i = tid >> 3, jq = tid & 7;
        const int rbase = i + 8 * jq;
        float acc[8] = {0, 0, 0, 0, 0, 0, 0, 0};
        for (int u = 0; u < 64; ++u) {
            float qv = qs[i][u];
            #pragma unroll
            for (int v = 0; v < 8; ++v) acc[v] += qv * ks[rbase + v][u];
        }
        #pragma unroll
        for (int v = 0; v < 8; ++v) lg[i][8 * jq + v] = acc[v];
    }
    // tail logit j = 64
    if (tid < 32) {
        const int i = tid;
        float acc = 0.f;
        for (int u = 0; u < 64; ++u) acc += qs[i][u] * ks[i + 64][u];
        lg[i][64] = acc;
    }
    __syncthreads();

    // softmax per row (32 rows, one thread each), then /8
    if (tid < 32) {
        float m = -1e30f;
        for (int j = 0; j < 65; ++j) m = fmaxf(m, lg[tid][j]);
        float s = 0.f;
        for (int j = 0; j < 65; ++j) {
            float e = __expf(lg[tid][j] - m);
            lg[tid][j] = e;
            s += e;
        }
        float inv = 0.125f / s;
        for (int j = 0; j < 65; ++j) lg[tid][j] *= inv;
    }
    __syncthreads();

    // PV: thread (i = tid>>3, fq = tid&7) computes f = 8*fq + u, u=0..7
    {
        const int i = tid >> 3, fq = tid & 7;
        float acc[8] = {0, 0, 0, 0, 0, 0, 0, 0};
        for (int j = 0; j <= 64; ++j) {
            float a = lg[i][j];
            const float* vr = &vs[i + j][8 * fq];
            #pragma unroll
            for (int u = 0; u < 8; ++u) acc[u] += a * vr[u];
        }
        float* dst = &X[(s0 + 4 * i) * EMB + h * FEAT + 8 * fq];
        *(float4*)&dst[0] = make_float4(acc[0], acc[1], acc[2], acc[3]);
        *(float4*)&dst[4] = make_float4(acc[4], acc[5], acc[6], acc[7]);
    }
}

// ---------------------------------------------------------------------------
extern "C" void kernel_launch(void* const* d_in, const int* in_sizes, int n_in,
                              void* d_out, int out_size, void* d_ws, size_t ws_size,
                              hipStream_t stream)
{
    const float* x    = (const float*)d_in[0];
    const float* Wq   = (const float*)d_in[1];
    const float* Wk   = (const float*)d_in[2];
    const float* Wv   = (const float*)d_in[3];
    const float* Wff1 = (const float*)d_in[4];
    const float* bff1 = (const float*)d_in[5];
    const float* Wff2 = (const float*)d_in[6];
    const float* bff2 = (const float*)d_in[7];
    float* out = (float*)d_out;

    const size_t MAT = (size_t)SEQ * EMB;   // 1,048,576 floats
    float* ws = (float*)d_ws;
    float* Qb = ws + 0 * MAT;
    float* Kb = ws + 1 * MAT;
    float* Vb = ws + 2 * MAT;
    float* XA = ws + 3 * MAT;
    float* Fb = ws + 4 * MAT;

    dim3 gg(EMB / 64, SEQ / 64);  // (8, 32)

    gemm64<false, false, false><<<gg, 512, 0, stream>>>(x, Wq, nullptr, nullptr, Qb, SEQ, EMB, EMB);
    gemm64<false, false, false><<<gg, 512, 0, stream>>>(x, Wk, nullptr, nullptr, Kb, SEQ, EMB, EMB);
    gemm64<false, false, false><<<gg, 512, 0, stream>>>(x, Wv, nullptr, nullptr, Vb, SEQ, EMB, EMB);

    attn_kernel<<<dim3(16, 4, 8), 256, 0, stream>>>(Qb, Kb, Vb, XA);

    gemm64<true, true, false><<<gg, 512, 0, stream>>>(XA, Wff1, bff1, nullptr, Fb, SEQ, EMB, EMB);
    gemm64<true, true, true ><<<gg, 512, 0, stream>>>(Fb, Wff2, bff2, XA, out, SEQ, EMB, EMB);
}

// Round 2
// 125.615 us; speedup vs baseline: 1.7715x; 1.7715x over previous
//
#include <hip/hip_runtime.h>
#include <hip/hip_bf16.h>

#define SEQ  2048
#define EMB  512
// attention window: j = 0..64, key pos = s - 128 + 4*j

typedef __attribute__((ext_vector_type(8))) short short8;
typedef __attribute__((ext_vector_type(4))) float f32x4;

__device__ __forceinline__ ushort f2b(float f) {
    union { __hip_bfloat16 h; ushort u; } cv;
    cv.h = __float2bfloat16(f);
    return cv.u;
}

__device__ __forceinline__ void async_copy16(const void* g, void* l) {
    __builtin_amdgcn_global_load_lds(
        (const __attribute__((address_space(1))) void*)g,
        (__attribute__((address_space(3))) void*)l, 16, 0, 0);
}

// ---------------------------------------------------------------------------
// convert x (fp32 [2048][512]) -> bf16
// ---------------------------------------------------------------------------
__global__ __launch_bounds__(256)
void cvt_x(const float* __restrict__ x, ushort* __restrict__ xb) {
    int i = (blockIdx.x * 256 + threadIdx.x) * 4;
    float4 v = *(const float4*)(x + i);
    ushort4 o;
    o.x = f2b(v.x); o.y = f2b(v.y); o.z = f2b(v.z); o.w = f2b(v.w);
    *(ushort4*)(xb + i) = o;
}

// ---------------------------------------------------------------------------
// transpose+convert weights: T[n][k] = bf16(W[k][n]); all are 512x512.
// grid (16,16,5), block (32,8)
// ---------------------------------------------------------------------------
__global__ __launch_bounds__(256)
void transpose_w(const float* W0, const float* W1, const float* W2,
                 const float* W3, const float* W4,
                 ushort* T0, ushort* T1, ushort* T2, ushort* T3, ushort* T4) {
    const float* W; ushort* T;
    switch (blockIdx.z) {
        case 0: W = W0; T = T0; break;
        case 1: W = W1; T = T1; break;
        case 2: W = W2; T = T2; break;
        case 3: W = W3; T = T3; break;
        default: W = W4; T = T4; break;
    }
    __shared__ float t[32][33];
    const int n0 = blockIdx.x * 32, k0 = blockIdx.y * 32;
    const int tx = threadIdx.x, ty = threadIdx.y;
    for (int r = ty; r < 32; r += 8)
        t[r][tx] = W[(k0 + r) * 512 + n0 + tx];
    __syncthreads();
    for (int r = ty; r < 32; r += 8)
        T[(n0 + r) * 512 + k0 + tx] = f2b(t[tx][r]);
}

// ---------------------------------------------------------------------------
// MFMA GEMM, A bf16 [M][512] row-major, BT bf16 [N][512] (i.e. B transposed),
// C = A*B (+bias,relu,+addsrc), out fp32 or bf16.
// Tile 64x64, K=512 staged in 2 chunks of 256; 4 waves, wave w owns
// k in [w*64, w*64+64) of each chunk (wave-level K-split, no inner barriers);
// LDS partial reduction in epilogue.
// LDS k-octet swizzle: LDS octet o of row r holds global octet o^(r&7) so
// fragment reads are <=2-way bank conflicts despite 512B row stride.
// ---------------------------------------------------------------------------
template<bool BIAS, bool RELU, bool ADDSRC, bool OUTBF16>
__global__ __launch_bounds__(256)
void gemm_bt(const ushort* __restrict__ A, const ushort* __restrict__ BT,
             const float* __restrict__ bias, const float* __restrict__ addsrc,
             void* __restrict__ C, int ldc)
{
    __shared__ __align__(16) char smem[65536];   // A tile 32KB | B tile 32KB
    const int tid = threadIdx.x;
    const int wv = tid >> 6, lane = tid & 63;
    const int lane15 = lane & 15, quad = lane >> 4;
    const int n0 = blockIdx.x * 64, m0 = blockIdx.y * 64;

    f32x4 acc[4][4];
    const f32x4 z4 = {0.f, 0.f, 0.f, 0.f};
    #pragma unroll
    for (int mi = 0; mi < 4; ++mi)
        #pragma unroll
        for (int ni = 0; ni < 4; ++ni) acc[mi][ni] = z4;

    const int rp_lane = lane >> 5;   // row within pair
    const int o_lane  = lane & 31;   // dest octet within 256-k row

    for (int kc = 0; kc < 2; ++kc) {
        // ---- stage A[64][256] + BT[64][256] via global_load_lds x16 ----
        #pragma unroll
        for (int i = 0; i < 16; ++i) {
            int gidx = wv * 16 + i;          // 0..63, each = 2 rows
            int isB  = gidx >= 32;
            int p    = isB ? gidx - 32 : gidx;
            int r    = p * 2 + rp_lane;      // tile row 0..63
            int g    = o_lane ^ (r & 7);     // source octet (swizzle)
            const ushort* src = isB ? (BT + (size_t)(n0 + r) * 512 + kc * 256 + g * 8)
                                    : (A  + (size_t)(m0 + r) * 512 + kc * 256 + g * 8);
            char* dst = smem + (isB ? 32768 : 0) + p * 1024;
            async_copy16(src, dst);
        }
        __syncthreads();   // drains vmcnt, data visible

        // ---- compute: wave w covers chunk k-octets [w*8, w*8+8) ----
        const char* As = smem;
        const char* Bs = smem + 32768;
        #pragma unroll
        for (int ks = 0; ks < 2; ++ks) {
            const int g   = wv * 8 + ks * 4 + quad;   // global octet in chunk
            const int oct = g ^ (lane & 7);           // swizzled LDS octet
            short8 a[4], b[4];
            #pragma unroll
            for (int mi = 0; mi < 4; ++mi)
                a[mi] = *(const short8*)(As + (mi * 16 + lane15) * 512 + oct * 16);
            #pragma unroll
            for (int ni = 0; ni < 4; ++ni)
                b[ni] = *(const short8*)(Bs + (ni * 16 + lane15) * 512 + oct * 16);
            #pragma unroll
            for (int mi = 0; mi < 4; ++mi)
                #pragma unroll
                for (int ni = 0; ni < 4; ++ni)
                    acc[mi][ni] = __builtin_amdgcn_mfma_f32_16x16x32_bf16(
                        a[mi], b[ni], acc[mi][ni], 0, 0, 0);
        }
        __syncthreads();   // compute done before LDS reuse
    }

    // ---- epilogue: 4-wave partial reduce through LDS ----
    float* red = (float*)smem;
    #pragma unroll
    for (int mi = 0; mi < 4; ++mi)
        #pragma unroll
        for (int ni = 0; ni < 4; ++ni)
            #pragma unroll
            for (int reg = 0; reg < 4; ++reg)
                red[wv * 4096 + (mi * 16 + quad * 4 + reg) * 64 + ni * 16 + lane15] =
                    acc[mi][ni][reg];
    __syncthreads();

    const int m  = tid >> 2;          // output row 0..63
    const int qb = (tid & 3) * 4;     // float4-col base
    const float4* r4 = (const float4*)smem;
    #pragma unroll
    for (int q = 0; q < 4; ++q) {
        int idx = m * 16 + qb + q;
        float4 s = r4[idx];
        float4 s1 = r4[idx + 1024], s2 = r4[idx + 2048], s3 = r4[idx + 3072];
        s.x += s1.x + s2.x + s3.x;  s.y += s1.y + s2.y + s3.y;
        s.z += s1.z + s2.z + s3.z;  s.w += s1.w + s2.w + s3.w;
        int colf = (qb + q) * 4;
        if (BIAS) {
            float4 bv = *(const float4*)&bias[n0 + colf];
            s.x += bv.x; s.y += bv.y; s.z += bv.z; s.w += bv.w;
        }
        if (RELU) {
            s.x = fmaxf(s.x, 0.f); s.y = fmaxf(s.y, 0.f);
            s.z = fmaxf(s.z, 0.f); s.w = fmaxf(s.w, 0.f);
        }
        if (ADDSRC) {
            float4 av = *(const float4*)&addsrc[(size_t)(m0 + m) * 512 + n0 + colf];
            s.x += av.x; s.y += av.y; s.z += av.z; s.w += av.w;
        }
        if (OUTBF16) {
            ushort4 o4;
            o4.x = f2b(s.x); o4.y = f2b(s.y); o4.z = f2b(s.z); o4.w = f2b(s.w);
            *(ushort4*)((ushort*)C + (size_t)(m0 + m) * ldc + n0 + colf) = o4;
        } else {
            *(float4*)((float*)C + (size_t)(m0 + m) * ldc + n0 + colf) = s;
        }
    }
}

// ---------------------------------------------------------------------------
// Dilated sliding-window attention (fp32), reads fused QKV [2048][1536].
// Block = (head h, residue r, 32 queries s = s0 + 4*i).
// Writes X fp32 [2048][512] and Xb bf16 (FFN input).
// ---------------------------------------------------------------------------
__global__ __launch_bounds__(256)
void attn_kernel(const float* __restrict__ QKV, float* __restrict__ X,
                 ushort* __restrict__ Xb)
{
    const int c = blockIdx.x;           // 0..15 chunk
    const int r = blockIdx.y;           // 0..3 residue
    const int h = blockIdx.z;           // 0..7 head
    const int tid = threadIdx.x;
    const int s0 = r + 4 * (c * 32);    // query i -> s = s0 + 4*i
    const int LDQ = 1536;

    __shared__ float qs[32][68];
    __shared__ float ks[96][65];
    __shared__ float vs[96][65];
    __shared__ float lg[32][66];

    for (int t = tid; t < 32 * 16; t += 256) {
        int i = t >> 4, fq = (t & 15) * 4;
        float4 v4 = *(const float4*)&QKV[(size_t)(s0 + 4 * i) * LDQ + h * 64 + fq];
        *(float4*)&qs[i][fq] = v4;
    }
    for (int t = tid; t < 96 * 16; t += 256) {
        int row = t >> 4, fq = (t & 15) * 4;
        int p = s0 - 128 + 4 * row;
        float4 kv = make_float4(0.f, 0.f, 0.f, 0.f);
        float4 vv = make_float4(0.f, 0.f, 0.f, 0.f);
        if (p >= 0 && p < SEQ) {
            kv = *(const float4*)&QKV[(size_t)p * LDQ + 512 + h * 64 + fq];
            vv = *(const float4*)&QKV[(size_t)p * LDQ + 1024 + h * 64 + fq];
        }
        ks[row][fq + 0] = kv.x; ks[row][fq + 1] = kv.y;
        ks[row][fq + 2] = kv.z; ks[row][fq + 3] = kv.w;
        vs[row][fq + 0] = vv.x; vs[row][fq + 1] = vv.y;
        vs[row][fq + 2] = vv.z; vs[row][fq + 3] = vv.w;
    }
    __syncthreads();

    {
        const int i = tid >> 3, jq = tid & 7;
        const int rbase = i + 8 * jq;
        float acc[8] = {0, 0, 0, 0, 0, 0, 0, 0};
        for (int u = 0; u < 64; ++u) {
            float qv = qs[i][u];
            #pragma unroll
            for (int v = 0; v < 8; ++v) acc[v] += qv * ks[rbase + v][u];
        }
        #pragma unroll
        for (int v = 0; v < 8; ++v) lg[i][8 * jq + v] = acc[v];
    }
    if (tid < 32) {
        const int i = tid;
        float acc = 0.f;
        for (int u = 0; u < 64; ++u) acc += qs[i][u] * ks[i + 64][u];
        lg[i][64] = acc;
    }
    __syncthreads();

    if (tid < 32) {
        float m = -1e30f;
        for (int j = 0; j < 65; ++j) m = fmaxf(m, lg[tid][j]);
        float s = 0.f;
        for (int j = 0; j < 65; ++j) {
            float e = __expf(lg[tid][j] - m);
            lg[tid][j] = e;
            s += e;
        }
        float inv = 0.125f / s;
        for (int j = 0; j < 65; ++j) lg[tid][j] *= inv;
    }
    __syncthreads();

    {
        const int i = tid >> 3, fq = tid & 7;
        float acc[8] = {0, 0, 0, 0, 0, 0, 0, 0};
        for (int j = 0; j <= 64; ++j) {
            float a = lg[i][j];
            const float* vr = &vs[i + j][8 * fq];
            #pragma unroll
            for (int u = 0; u < 8; ++u) acc[u] += a * vr[u];
        }
        size_t base = (size_t)(s0 + 4 * i) * EMB + h * 64 + 8 * fq;
        *(float4*)&X[base]     = make_float4(acc[0], acc[1], acc[2], acc[3]);
        *(float4*)&X[base + 4] = make_float4(acc[4], acc[5], acc[6], acc[7]);
        ushort4 b0, b1;
        b0.x = f2b(acc[0]); b0.y = f2b(acc[1]); b0.z = f2b(acc[2]); b0.w = f2b(acc[3]);
        b1.x = f2b(acc[4]); b1.y = f2b(acc[5]); b1.z = f2b(acc[6]); b1.w = f2b(acc[7]);
        *(ushort4*)&Xb[base]     = b0;
        *(ushort4*)&Xb[base + 4] = b1;
    }
}

// ---------------------------------------------------------------------------
extern "C" void kernel_launch(void* const* d_in, const int* in_sizes, int n_in,
                              void* d_out, int out_size, void* d_ws, size_t ws_size,
                              hipStream_t stream)
{
    const float* x    = (const float*)d_in[0];
    const float* Wq   = (const float*)d_in[1];
    const float* Wk   = (const float*)d_in[2];
    const float* Wv   = (const float*)d_in[3];
    const float* Wff1 = (const float*)d_in[4];
    const float* bff1 = (const float*)d_in[5];
    const float* Wff2 = (const float*)d_in[6];
    const float* bff2 = (const float*)d_in[7];
    float* out = (float*)d_out;

    char* w = (char*)d_ws;
    ushort* xb    = (ushort*)(w);                        // 2 MB  [2048][512]
    ushort* WqkvT = (ushort*)(w + (2ull  << 20));        // 1.5MB [1536][512]
    ushort* W1T   = (ushort*)(w + (4ull  << 20));        // 0.5MB [512][512]
    ushort* W2T   = (ushort*)(w + (5ull  << 20));        // 0.5MB
    float*  QKV   = (float*) (w + (6ull  << 20));        // 12 MB [2048][1536]
    float*  XA    = (float*) (w + (18ull << 20));        // 4 MB  [2048][512]
    ushort* XAb   = (ushort*)(w + (22ull << 20));        // 2 MB
    ushort* Fb    = (ushort*)(w + (24ull << 20));        // 2 MB

    cvt_x<<<SEQ * EMB / 1024, 256, 0, stream>>>(x, xb);
    transpose_w<<<dim3(16, 16, 5), dim3(32, 8), 0, stream>>>(
        Wq, Wk, Wv, Wff1, Wff2,
        WqkvT, WqkvT + 512 * 512, WqkvT + 1024 * 512, W1T, W2T);

    // QKV: [2048][1536] = xb * [WqkvT]^T
    gemm_bt<false, false, false, false><<<dim3(24, 32), 256, 0, stream>>>(
        xb, WqkvT, nullptr, nullptr, QKV, 1536);

    attn_kernel<<<dim3(16, 4, 8), 256, 0, stream>>>(QKV, XA, XAb);

    // FFN1: relu(XA*Wff1 + b1) -> bf16
    gemm_bt<true, true, false, true><<<dim3(8, 32), 256, 0, stream>>>(
        XAb, W1T, bff1, nullptr, Fb, 512);
    // FFN2: XA + relu(F*Wff2 + b2) -> fp32 out
    gemm_bt<true, true, true, false><<<dim3(8, 32), 256, 0, stream>>>(
        Fb, W2T, bff2, XA, out, 512);
}

// Round 3
// 109.975 us; speedup vs baseline: 2.0234x; 1.1422x over previous
//
#include <hip/hip_runtime.h>
#include <hip/hip_bf16.h>

#define SEQ 2048
#define EMB 512

typedef __attribute__((ext_vector_type(8))) short short8;
typedef __attribute__((ext_vector_type(4))) float f32x4;

__device__ __forceinline__ ushort f2b(float f) {
    union { __hip_bfloat16 h; ushort u; } cv;
    cv.h = __float2bfloat16(f);
    return cv.u;
}

__device__ __forceinline__ void async_copy16(const void* g, void* l) {
    __builtin_amdgcn_global_load_lds(
        (const __attribute__((address_space(1))) void*)g,
        (__attribute__((address_space(3))) void*)l, 16, 0, 0);
}

// ---------------------------------------------------------------------------
// convert x (fp32 [2048][512]) -> bf16
// ---------------------------------------------------------------------------
__global__ __launch_bounds__(256)
void cvt_x(const float* __restrict__ x, ushort* __restrict__ xb) {
    int i = (blockIdx.x * 256 + threadIdx.x) * 4;
    float4 v = *(const float4*)(x + i);
    ushort4 o;
    o.x = f2b(v.x); o.y = f2b(v.y); o.z = f2b(v.z); o.w = f2b(v.w);
    *(ushort4*)(xb + i) = o;
}

// ---------------------------------------------------------------------------
// transpose+convert weights: T[n][k] = bf16(W[k][n]); all 512x512.
// grid (16,16,5), block (32,8)
// ---------------------------------------------------------------------------
__global__ __launch_bounds__(256)
void transpose_w(const float* W0, const float* W1, const float* W2,
                 const float* W3, const float* W4,
                 ushort* T0, ushort* T1, ushort* T2, ushort* T3, ushort* T4) {
    const float* W; ushort* T;
    switch (blockIdx.z) {
        case 0: W = W0; T = T0; break;
        case 1: W = W1; T = T1; break;
        case 2: W = W2; T = T2; break;
        case 3: W = W3; T = T3; break;
        default: W = W4; T = T4; break;
    }
    __shared__ float t[32][33];
    const int n0 = blockIdx.x * 32, k0 = blockIdx.y * 32;
    const int tx = threadIdx.x, ty = threadIdx.y;
    for (int r = ty; r < 32; r += 8)
        t[r][tx] = W[(k0 + r) * 512 + n0 + tx];
    __syncthreads();
    for (int r = ty; r < 32; r += 8)
        T[(n0 + r) * 512 + k0 + tx] = f2b(t[tx][r]);
}

// ---------------------------------------------------------------------------
// MFMA GEMM v2: A bf16 [M][512], BT bf16 [N][512]; C = A*B (+bias,relu,+add).
// 64x64 block tile, 4 waves each owning a 32x32 quadrant over full K.
// K chunked by 64, double-buffered LDS (16KB/buf), global_load_lds staging,
// XOR k-octet swizzle (row stride 128B -> 2-way max on ds_read_b128).
// ---------------------------------------------------------------------------
template<bool BIAS, bool RELU, bool ADDSRC, bool OUTBF16>
__global__ __launch_bounds__(256)
void gemm_bt(const ushort* __restrict__ A, const ushort* __restrict__ BT,
             const float* __restrict__ bias, const float* __restrict__ addsrc,
             void* __restrict__ C, int ldc)
{
    __shared__ __align__(16) ushort As[2][64][64];
    __shared__ __align__(16) ushort Bs[2][64][64];
    const int tid = threadIdx.x;
    const int wv = tid >> 6, lane = tid & 63;
    const int lane15 = lane & 15, quad = lane >> 4;
    const int n0 = blockIdx.x * 64, m0 = blockIdx.y * 64;
    const int wm = wv & 1, wn = wv >> 1;
    const int srow = lane >> 3;      // 0..7
    const int soct = lane & 7;       // dest oct slot

    f32x4 acc[2][2];
    const f32x4 z4 = {0.f, 0.f, 0.f, 0.f};
    acc[0][0] = z4; acc[0][1] = z4; acc[1][0] = z4; acc[1][1] = z4;

    auto stage = [&](int buf, int kc) {
        #pragma unroll
        for (int half = 0; half < 2; ++half) {
            int r0 = wv * 16 + half * 8;
            int r  = r0 + srow;
            int g  = soct ^ (r & 7);
            async_copy16(A + (size_t)(m0 + r) * 512 + kc * 64 + g * 8,
                         &As[buf][r0][0]);
            async_copy16(BT + (size_t)(n0 + r) * 512 + kc * 64 + g * 8,
                         &Bs[buf][r0][0]);
        }
    };
    auto compute = [&](int buf) {
        #pragma unroll
        for (int ks = 0; ks < 2; ++ks) {
            short8 a[2], b[2];
            const int oct = ((ks * 4 + quad) ^ (lane15 & 7)) * 8;
            #pragma unroll
            for (int mi = 0; mi < 2; ++mi)
                a[mi] = *(const short8*)&As[buf][wm * 32 + mi * 16 + lane15][oct];
            #pragma unroll
            for (int ni = 0; ni < 2; ++ni)
                b[ni] = *(const short8*)&Bs[buf][wn * 32 + ni * 16 + lane15][oct];
            #pragma unroll
            for (int mi = 0; mi < 2; ++mi)
                #pragma unroll
                for (int ni = 0; ni < 2; ++ni)
                    acc[mi][ni] = __builtin_amdgcn_mfma_f32_16x16x32_bf16(
                        a[mi], b[ni], acc[mi][ni], 0, 0, 0);
        }
    };

    stage(0, 0);
    __syncthreads();
    for (int kc = 0; kc < 8; ++kc) {
        if (kc < 7) stage((kc + 1) & 1, kc + 1);
        compute(kc & 1);
        __syncthreads();
    }

    #pragma unroll
    for (int mi = 0; mi < 2; ++mi)
        #pragma unroll
        for (int ni = 0; ni < 2; ++ni)
            #pragma unroll
            for (int reg = 0; reg < 4; ++reg) {
                int row = m0 + wm * 32 + mi * 16 + quad * 4 + reg;
                int col = n0 + wn * 32 + ni * 16 + lane15;
                float v = acc[mi][ni][reg];
                if (BIAS) v += bias[col];
                if (RELU) v = fmaxf(v, 0.f);
                if (ADDSRC) v += addsrc[(size_t)row * ldc + col];
                if (OUTBF16) ((ushort*)C)[(size_t)row * ldc + col] = f2b(v);
                else         ((float*)C)[(size_t)row * ldc + col] = v;
            }
}

// ---------------------------------------------------------------------------
// Vt transpose: Vtg[h][r][f][u] = V[u*4+r][h*64+f] (V = QKVb cols 1024..1535).
// grid (32,8), block 256.
// ---------------------------------------------------------------------------
__global__ __launch_bounds__(256)
void vt_transpose(const ushort* __restrict__ QKVb, ushort* __restrict__ Vtg)
{
    const int sb = blockIdx.x, h = blockIdx.y;
    const int s0 = sb * 64;
    const int tid = threadIdx.x;
    __shared__ ushort tile[64][72];
    #pragma unroll
    for (int it = 0; it < 2; ++it) {
        int row = (tid >> 3) + 32 * it;
        int o = tid & 7;
        *(short8*)&tile[row][o * 8] =
            *(const short8*)&QKVb[(size_t)(s0 + row) * 1536 + 1024 + h * 64 + o * 8];
    }
    __syncthreads();
    const int f = tid >> 2, r = tid & 3;
    ushort tmp[16];
    #pragma unroll
    for (int k = 0; k < 16; ++k) tmp[k] = tile[4 * k + r][f];
    size_t base = (((size_t)h * 4 + r) * 64 + f) * 512 + s0 / 4;
    *(short8*)&Vtg[base]     = *(short8*)&tmp[0];
    *(short8*)&Vtg[base + 8] = *(short8*)&tmp[8];
}

// ---------------------------------------------------------------------------
// MFMA dilated sliding-window attention.
// Block (c,r,h): 32 queries s = s0+4i, s0 = r+128c; keys t in [0,96),
// p = s0-128+4t (OOB rows zero -> logit 0, matching reference zero-pad).
// logits 32x96 = Q*K^T (MFMA) -> masked exp (no max-sub; |logit| small)
// -> unnormalized P bf16 in LDS -> PV MFMA with pre-transposed Vt ->
// epilogue scales by 0.125/rowsum.
// ---------------------------------------------------------------------------
__global__ __launch_bounds__(256)
void attn_kernel(const ushort* __restrict__ QKVb, const ushort* __restrict__ Vtg,
                 float* __restrict__ X, ushort* __restrict__ Xb)
{
    const int c = blockIdx.x, r = blockIdx.y, h = blockIdx.z;
    const int tid = threadIdx.x;
    const int wv = tid >> 6, lane = tid & 63;
    const int lane15 = lane & 15, quad = lane >> 4;
    const int s0 = r + 128 * c;
    const int wm = wv & 1, nh = wv >> 1;

    __shared__ __align__(16) ushort Qs[32][64];     // 4 KB  (8 octs, swizzled)
    __shared__ __align__(16) ushort Ks[96][64];     // 12 KB
    __shared__ __align__(16) ushort Vts[64][128];   // 16 KB (12 octs in 16)
    __shared__ __align__(16) ushort Ps[32][128];    // 8 KB
    __shared__ float psum[2][32];

    // ---- stage Q ----
    {
        int i = tid >> 3, o = tid & 7, g = o ^ (i & 7);
        *(short8*)&Qs[i][o * 8] =
            *(const short8*)&QKVb[(size_t)(s0 + 4 * i) * 1536 + h * 64 + g * 8];
    }
    // ---- stage K (zero-fill OOB rows) ----
    #pragma unroll
    for (int j = 0; j < 3; ++j) {
        int row = (tid >> 3) + 32 * j;
        int o = tid & 7, g = o ^ (row & 7);
        int p = s0 - 128 + 4 * row;
        short8 v = {0, 0, 0, 0, 0, 0, 0, 0};
        if (p >= 0 && p < SEQ)
            v = *(const short8*)&QKVb[(size_t)p * 1536 + 512 + h * 64 + g * 8];
        *(short8*)&Ks[row][o * 8] = v;
    }
    // ---- stage Vt rows (u window contiguous thanks to residue split) ----
    {
        const int u0 = 32 * c - 32;
        const int f = tid & 63;
        #pragma unroll
        for (int j = 0; j < 3; ++j) {
            int o = (tid >> 6) + 4 * j;          // 0..11
            int u = u0 + 8 * o;
            short8 v = {0, 0, 0, 0, 0, 0, 0, 0};
            if (u >= 0 && u < 512)
                v = *(const short8*)&Vtg[(((size_t)h * 4 + r) * 64 + f) * 512 + u];
            *(short8*)&Vts[f][(o ^ (f & 7)) * 8] = v;
        }
    }
    __syncthreads();

    // ---- QK: wave (wm, nh): m-tile wm, n-tiles 3*nh+{0,1,2} ----
    f32x4 lacc[3];
    const f32x4 z4 = {0.f, 0.f, 0.f, 0.f};
    lacc[0] = z4; lacc[1] = z4; lacc[2] = z4;
    short8 qa[2];
    #pragma unroll
    for (int kt = 0; kt < 2; ++kt)
        qa[kt] = *(const short8*)
            &Qs[wm * 16 + lane15][((kt * 4 + quad) ^ (lane15 & 7)) * 8];
    #pragma unroll
    for (int tt = 0; tt < 3; ++tt) {
        int nt = 3 * nh + tt;
        #pragma unroll
        for (int kt = 0; kt < 2; ++kt) {
            short8 kb = *(const short8*)
                &Ks[nt * 16 + lane15][((kt * 4 + quad) ^ (lane15 & 7)) * 8];
            lacc[tt] = __builtin_amdgcn_mfma_f32_16x16x32_bf16(qa[kt], kb, lacc[tt], 0, 0, 0);
        }
    }

    // ---- masked exp, partial row sums, write unnormalized P (bf16) ----
    const int rowi = wm * 16 + quad * 4;
    float part[4] = {0.f, 0.f, 0.f, 0.f};
    #pragma unroll
    for (int tt = 0; tt < 3; ++tt) {
        int t = (3 * nh + tt) * 16 + lane15;
        #pragma unroll
        for (int reg = 0; reg < 4; ++reg) {
            int i = rowi + reg;
            int d = t - i;
            float e = 0.f;
            if (d >= 0 && d <= 64) e = __expf(lacc[tt][reg]);
            part[reg] += e;
            int ol = (t >> 3) ^ (i & 7);
            Ps[i][ol * 8 + (t & 7)] = f2b(e);
        }
    }
    #pragma unroll
    for (int reg = 0; reg < 4; ++reg) {
        float v = part[reg];
        v += __shfl_xor(v, 1);
        v += __shfl_xor(v, 2);
        v += __shfl_xor(v, 4);
        v += __shfl_xor(v, 8);
        part[reg] = v;
    }
    if (lane15 == 0) {
        #pragma unroll
        for (int reg = 0; reg < 4; ++reg)
            psum[nh][rowi + reg] = part[reg];
    }
    __syncthreads();

    // ---- PV: wave (wm, nh): f-tiles 2*nh+{0,1}, k-chains 0..2 ----
    f32x4 oacc[2];
    oacc[0] = z4; oacc[1] = z4;
    short8 pa[3];
    #pragma unroll
    for (int kc = 0; kc < 3; ++kc)
        pa[kc] = *(const short8*)
            &Ps[wm * 16 + lane15][((kc * 4 + quad) ^ (lane15 & 7)) * 8];
    #pragma unroll
    for (int ft = 0; ft < 2; ++ft) {
        int fr = (2 * nh + ft) * 16 + lane15;
        #pragma unroll
        for (int kc = 0; kc < 3; ++kc) {
            short8 vb = *(const short8*)
                &Vts[fr][((kc * 4 + quad) ^ (fr & 7)) * 8];
            oacc[ft] = __builtin_amdgcn_mfma_f32_16x16x32_bf16(pa[kc], vb, oacc[ft], 0, 0, 0);
        }
    }

    // ---- epilogue: scale by 0.125/rowsum, write fp32 X + bf16 Xb ----
    #pragma unroll
    for (int reg = 0; reg < 4; ++reg) {
        int i = rowi + reg;
        float inv = 0.125f / (psum[0][i] + psum[1][i]);
        #pragma unroll
        for (int ft = 0; ft < 2; ++ft) {
            int f = (2 * nh + ft) * 16 + lane15;
            float v = oacc[ft][reg] * inv;
            size_t idx = (size_t)(s0 + 4 * i) * 512 + h * 64 + f;
            X[idx] = v;
            Xb[idx] = f2b(v);
        }
    }
}

// ---------------------------------------------------------------------------
extern "C" void kernel_launch(void* const* d_in, const int* in_sizes, int n_in,
                              void* d_out, int out_size, void* d_ws, size_t ws_size,
                              hipStream_t stream)
{
    const float* x    = (const float*)d_in[0];
    const float* Wq   = (const float*)d_in[1];
    const float* Wk   = (const float*)d_in[2];
    const float* Wv   = (const float*)d_in[3];
    const float* Wff1 = (const float*)d_in[4];
    const float* bff1 = (const float*)d_in[5];
    const float* Wff2 = (const float*)d_in[6];
    const float* bff2 = (const float*)d_in[7];
    float* out = (float*)d_out;

    char* w = (char*)d_ws;
    ushort* xb    = (ushort*)(w);                    // 2 MB   [2048][512]
    ushort* WqkvT = (ushort*)(w + (2ull  << 20));    // 1.5 MB [1536][512]
    ushort* W1T   = (ushort*)(w + (3584ull << 10));  // 0.5 MB [512][512]
    ushort* W2T   = (ushort*)(w + (4ull  << 20));    // 0.5 MB
    ushort* QKVb  = (ushort*)(w + (5ull  << 20));    // 6 MB   [2048][1536]
    ushort* Vtg   = (ushort*)(w + (11ull << 20));    // 2 MB   [8][4][64][512]
    float*  X     = (float*) (w + (13ull << 20));    // 4 MB   [2048][512]
    ushort* Xb    = (ushort*)(w + (17ull << 20));    // 2 MB
    ushort* Fb    = (ushort*)(w + (19ull << 20));    // 2 MB

    cvt_x<<<SEQ * EMB / 1024, 256, 0, stream>>>(x, xb);
    transpose_w<<<dim3(16, 16, 5), dim3(32, 8), 0, stream>>>(
        Wq, Wk, Wv, Wff1, Wff2,
        WqkvT, WqkvT + 512 * 512, WqkvT + 1024 * 512, W1T, W2T);

    // QKVb[2048][1536] = xb * Wqkv  (bf16 out)
    gemm_bt<false, false, false, true><<<dim3(24, 32), 256, 0, stream>>>(
        xb, WqkvT, nullptr, nullptr, QKVb, 1536);

    vt_transpose<<<dim3(32, 8), 256, 0, stream>>>(QKVb, Vtg);

    attn_kernel<<<dim3(16, 4, 8), 256, 0, stream>>>(QKVb, Vtg, X, Xb);

    // FFN1: relu(Xa*W1 + b1) -> bf16
    gemm_bt<true, true, false, true><<<dim3(8, 32), 256, 0, stream>>>(
        Xb, W1T, bff1, nullptr, Fb, 512);
    // FFN2: Xa + relu(F*W2 + b2) -> fp32
    gemm_bt<true, true, true, false><<<dim3(8, 32), 256, 0, stream>>>(
        Fb, W2T, bff2, X, out, 512);
}